// Round 5
// baseline (1027.959 us; speedup 1.0000x reference)
//
#include <hip/hip_runtime.h>
#include <hip/hip_bf16.h>
#include <math.h>

#define B 8
#define C 256
#define HEADS 8
#define D 32
#define NPIX 1024
#define SCALE 0.17677669529663687f   // 1/sqrt(32)
#define LOG2E 1.4426950408889634f

typedef unsigned int uint;
typedef unsigned short u16;

static __device__ inline u16 f2bf(float f) {   // RNE f32->bf16
  uint u = __float_as_uint(f);
  return (u16)((u + 0x7fffu + ((u >> 16) & 1u)) >> 16);
}
static __device__ inline float bf_lo(uint u) { return __uint_as_float(u << 16); }
static __device__ inline float bf_hi(uint u) { return __uint_as_float(u & 0xffff0000u); }

// ---------------------------------------------------------------------------
// K1: QKV projection. x fp32 [b][c][pix], w fp32 [o][c].
// Out: Q/K/V[b][h][pix][d] bf16 (uint pairs).
// ---------------------------------------------------------------------------
__global__ __launch_bounds__(256) void k_qkv(
    const float* __restrict__ x, const float* __restrict__ wqkv,
    uint* __restrict__ Q, uint* __restrict__ Kk, uint* __restrict__ V) {
  const int og = blockIdx.x;   // 0..47
  const int b  = blockIdx.y;
  const int tid = threadIdx.x;
  const int o0 = og * 16;

  float acc[4][16];
#pragma unroll
  for (int p = 0; p < 4; ++p)
#pragma unroll
    for (int o = 0; o < 16; ++o) acc[p][o] = 0.f;

  const float* xb = x + (size_t)b * C * NPIX;
  for (int c = 0; c < C; ++c) {
    float xv[4];
#pragma unroll
    for (int p = 0; p < 4; ++p)
      xv[p] = xb[c * NPIX + p * 256 + tid];
#pragma unroll
    for (int o = 0; o < 16; ++o) {
      float wv = wqkv[(o0 + o) * C + c];   // block-uniform -> scalar load
#pragma unroll
      for (int p = 0; p < 4; ++p) acc[p][o] += xv[p] * wv;
    }
  }

  const int part = og >> 4;            // 0=q 1=k 2=v
  const int ch0  = (og & 15) * 16;
  const int hh   = ch0 >> 5;
  const int dd0  = ch0 & 31;           // 0 or 16
  uint* dst = (part == 0 ? Q : (part == 1 ? Kk : V)) +
              ((size_t)(b * HEADS + hh) * NPIX) * (D / 2) + dd0 / 2;
#pragma unroll
  for (int p = 0; p < 4; ++p) {
    const int pix = p * 256 + tid;
    uint pk[8];
#pragma unroll
    for (int q2 = 0; q2 < 8; ++q2)
      pk[q2] = (uint)f2bf(acc[p][2 * q2]) | ((uint)f2bf(acc[p][2 * q2 + 1]) << 16);
    uint4* dp = (uint4*)(dst + (size_t)pix * (D / 2));
    dp[0] = make_uint4(pk[0], pk[1], pk[2], pk[3]);
    dp[1] = make_uint4(pk[4], pk[5], pk[6], pk[7]);
  }
}

// ---------------------------------------------------------------------------
// K1b: diag_vec[b][c] = (SCALE/8) * sum_h sum_t q[b,h,33t,c]*k[b,h,33t,c]
// ---------------------------------------------------------------------------
__global__ __launch_bounds__(256) void k_diag(
    const uint* __restrict__ Q, const uint* __restrict__ Kk,
    float* __restrict__ diagv) {
  const int b = blockIdx.x, tid = threadIdx.x;
  const int hh = tid >> 5, dd = tid & 31;
  const uint* qb = Q + (size_t)(b * HEADS + hh) * NPIX * (D / 2);
  const uint* kb = Kk + (size_t)(b * HEADS + hh) * NPIX * (D / 2);
  float s = 0.f;
#pragma unroll 4
  for (int t = 0; t < 32; ++t) {
    uint qu = qb[t * 33 * (D / 2) + dd / 2];
    uint ku = kb[t * 33 * (D / 2) + dd / 2];
    float qv = (dd & 1) ? bf_hi(qu) : bf_lo(qu);
    float kv = (dd & 1) ? bf_hi(ku) : bf_lo(ku);
    s += qv * kv;
  }
  __shared__ float red[256];
  red[tid] = s;
  __syncthreads();
  if (tid < 32) {
    float v = 0.f;
#pragma unroll
    for (int h8 = 0; h8 < 8; ++h8) v += red[h8 * 32 + tid];
    diagv[b * 32 + tid] = v * (SCALE / 8.f);
  }
}

// ---------------------------------------------------------------------------
// K1c: colsum[b][h][d] = sum_j V[b][h][j][d]
// ---------------------------------------------------------------------------
__global__ __launch_bounds__(256) void k_colsum(
    const uint* __restrict__ V, float* __restrict__ colsum) {
  const int hh = blockIdx.x, b = blockIdx.y, tid = threadIdx.x;
  const int dd = tid & 31, jg = tid >> 5;
  const uint* vb = V + (size_t)(b * HEADS + hh) * NPIX * (D / 2);
  float s = 0.f;
  for (int j = 0; j < 128; ++j) {
    uint vu = vb[(jg * 128 + j) * (D / 2) + dd / 2];
    s += (dd & 1) ? bf_hi(vu) : bf_lo(vu);
  }
  __shared__ float red[256];
  red[tid] = s;
  __syncthreads();
  if (tid < 32) {
    float v = 0.f;
#pragma unroll
    for (int g = 0; g < 8; ++g) v += red[g * 32 + tid];
    colsum[(b * HEADS + hh) * D + tid] = v;
  }
}

// ---------------------------------------------------------------------------
// K2: attention, 1 thread = 1 query row. No-max softmax, clamped exponent.
// AO bf16, channel-major.
// ---------------------------------------------------------------------------
__global__ __launch_bounds__(256) void k_attn(
    const uint* __restrict__ Q, const uint* __restrict__ Kk,
    const uint* __restrict__ V, const float* __restrict__ diagv,
    const float* __restrict__ colsum, u16* __restrict__ AO) {
  const int b = blockIdx.z, hh = blockIdx.y;
  const int i = blockIdx.x * 256 + threadIdx.x;
  const int bh = b * HEADS + hh;

  const uint* qp = Q + ((size_t)bh * NPIX + i) * (D / 2);
  float qs[D];
#pragma unroll
  for (int m = 0; m < 16; ++m) {
    uint uu = qp[m];
    qs[2 * m]     = bf_lo(uu) * (SCALE * LOG2E);
    qs[2 * m + 1] = bf_hi(uu) * (SCALE * LOG2E);
  }

  const uint* Kb = Kk + (size_t)bh * NPIX * (D / 2);
  const uint* Vb = V + (size_t)bh * NPIX * (D / 2);

  float acc[D];
#pragma unroll
  for (int d = 0; d < D; ++d) acc[d] = 0.f;
  float l = 0.f;

  for (int j = 0; j < NPIX; ++j) {
    const uint* kr = Kb + j * (D / 2);   // wave-uniform
    float s = 0.f;
#pragma unroll
    for (int m = 0; m < 16; ++m) {
      uint uu = kr[m];
      s += qs[2 * m] * bf_lo(uu) + qs[2 * m + 1] * bf_hi(uu);
    }
    s = fminf(fmaxf(s, -80.f), 80.f);
    float p = exp2f(s);
    l += p;
    const uint* vr = Vb + j * (D / 2);
#pragma unroll
    for (int m = 0; m < 16; ++m) {
      uint uu = vr[m];
      acc[2 * m]     += p * bf_lo(uu);
      acc[2 * m + 1] += p * bf_hi(uu);
    }
  }

  const float rl = 1.f / l;
  const float coeff = (i < 32) ? 0.3f * diagv[b * 32 + i] : 0.f;
  const float* cs = colsum + bh * D;
  u16* ao = AO + ((size_t)b * C + hh * D) * NPIX + i;
#pragma unroll
  for (int d = 0; d < D; ++d)
    ao[(size_t)d * NPIX] = f2bf(acc[d] * rl + coeff * cs[d]);
}

// ---------------------------------------------------------------------------
// K3: gate. One block per (b, row h); 16 distinct gate values per row.
// ---------------------------------------------------------------------------
__global__ __launch_bounds__(256) void k_gate(
    const float* __restrict__ x,
    const float* __restrict__ wg1, const float* __restrict__ bg1,
    const float* __restrict__ wg2, const float* __restrict__ bg2,
    float* __restrict__ gate) {
  const int h = blockIdx.x, b = blockIdx.y, tid = threadIdx.x;
  __shared__ float pl[16 * 257];   // 16.4 KB
  __shared__ float gl[16 * 65];

  {  // stage pooled: thread = channel c
    const int c = tid;
    const float* row = x + ((size_t)(b * C + c) * NPIX + h * 32);
    float v[32];
#pragma unroll
    for (int m = 0; m < 32; ++m) v[m] = row[m];
#pragma unroll
    for (int k = 0; k < 16; ++k) pl[k * 257 + c] = fabsf(v[k] - v[31 - k]);
  }
  __syncthreads();

  const int o16 = tid >> 4, k = tid & 15;
#pragma unroll 1
  for (int p = 0; p < 4; ++p) {
    const int o = p * 16 + o16;
    float a = bg1[o];
    const float* wr = wg1 + o * C;
    for (int c = 0; c < C; ++c)
      a += wr[c] * pl[k * 257 + c];
    gl[k * 65 + o] = 0.5f * a * (1.f + erff(a * 0.70710678118654752f));
  }
  __syncthreads();

  if (tid < 16) {
    float s = bg2[0];
    for (int o = 0; o < 64; ++o)
      s += wg2[o] * gl[tid * 65 + o];
    gate[(b * 32 + h) * 16 + tid] = 1.f / (1.f + expf(-s));
  }
}

// ---------------------------------------------------------------------------
// K4: epilogue projection with gate. OUTPUT IS FP32.
// ---------------------------------------------------------------------------
__global__ __launch_bounds__(256) void k_out(
    const u16* __restrict__ AO, const float* __restrict__ wout,
    const float* __restrict__ bout, const float* __restrict__ gate,
    float* __restrict__ out) {
  const int pc = blockIdx.x, og = blockIdx.y, b = blockIdx.z;
  const int tid = threadIdx.x;
  const int pix = pc * 256 + tid;

  float acc[16];
#pragma unroll
  for (int o = 0; o < 16; ++o) acc[o] = 0.f;

  const u16* ab = AO + (size_t)b * C * NPIX + pix;
  for (int c = 0; c < C; ++c) {
    float av = __uint_as_float(((uint)ab[(size_t)c * NPIX]) << 16);
#pragma unroll
    for (int o = 0; o < 16; ++o)
      acc[o] += wout[(og * 16 + o) * C + c] * av;
  }

  const float gf = 1.f + gate[(b * 32 + (pix >> 5)) * 16 + ((pix & 31) >> 1)];
#pragma unroll
  for (int o = 0; o < 16; ++o) {
    float r = acc[o] * gf + bout[og * 16 + o];
    out[((size_t)b * C + og * 16 + o) * NPIX + pix] = r;
  }
}

// ---------------------------------------------------------------------------
extern "C" void kernel_launch(void* const* d_in, const int* in_sizes, int n_in,
                              void* d_out, int out_size, void* d_ws, size_t ws_size,
                              hipStream_t stream) {
  const float* x    = (const float*)d_in[0];
  const float* wqkv = (const float*)d_in[1];
  const float* wout = (const float*)d_in[2];
  const float* bout = (const float*)d_in[3];
  const float* wg1  = (const float*)d_in[4];
  const float* bg1  = (const float*)d_in[5];
  const float* wg2  = (const float*)d_in[6];
  const float* bg2  = (const float*)d_in[7];
  float* out = (float*)d_out;   // fp32 output (matches reference dtype)

  // workspace (~16.05 MB): Q,K,V bf16 4MB each; AO bf16 4MB; small fp32 tails.
  const size_t SZ_U = (size_t)B * HEADS * NPIX * (D / 2);  // uints per QKV buf
  uint* Q  = (uint*)d_ws;
  uint* Kq = Q + SZ_U;
  uint* V  = Kq + SZ_U;
  u16* AO  = (u16*)(V + SZ_U);
  float* DIAG = (float*)(AO + (size_t)B * C * NPIX);
  float* COL  = DIAG + 256;
  float* GATE = COL + 2048;

  hipLaunchKernelGGL(k_qkv, dim3(48, B), dim3(256), 0, stream, x, wqkv, Q, Kq, V);
  hipLaunchKernelGGL(k_diag, dim3(B), dim3(256), 0, stream, Q, Kq, DIAG);
  hipLaunchKernelGGL(k_colsum, dim3(HEADS, B), dim3(256), 0, stream, V, COL);
  hipLaunchKernelGGL(k_attn, dim3(4, HEADS, B), dim3(256), 0, stream,
                     Q, Kq, V, DIAG, COL, AO);
  hipLaunchKernelGGL(k_gate, dim3(32, B), dim3(256), 0, stream,
                     x, wg1, bg1, wg2, bg2, GATE);
  hipLaunchKernelGGL(k_out, dim3(4, 16, B), dim3(256), 0, stream,
                     AO, wout, bout, GATE, out);
}

// Round 6
// 320.084 us; speedup vs baseline: 3.2115x; 3.2115x over previous
//
#include <hip/hip_runtime.h>
#include <hip/hip_bf16.h>
#include <math.h>

#define B 8
#define C 256
#define HEADS 8
#define D 32
#define NPIX 1024
#define SCALE 0.17677669529663687f   // 1/sqrt(32)
#define LOG2E 1.4426950408889634f
#define PPITCH 68                    // fp32 LDS pitch: 68*4=272 B (16B-aligned rows, 2-way banks)

typedef unsigned int uint;
typedef unsigned short u16;
typedef __attribute__((ext_vector_type(8))) short bf16x8;
typedef __attribute__((ext_vector_type(4))) float f32x4;

static __device__ inline u16 f2bf(float f) {   // RNE f32->bf16
  uint u = __float_as_uint(f);
  return (u16)((u + 0x7fffu + ((u >> 16) & 1u)) >> 16);
}
static __device__ inline float bf_lo(uint u) { return __uint_as_float(u << 16); }
static __device__ inline float bf_hi(uint u) { return __uint_as_float(u & 0xffff0000u); }

// ---------------------------------------------------------------------------
// K1: QKV projection. x fp32 [b][c][pix], w fp32 [o][c].
// Q/K: [bh][pix][d] bf16.  V: stored TRANSPOSED as VT[bh][d][pix] bf16.
// ---------------------------------------------------------------------------
__global__ __launch_bounds__(256) void k_qkv(
    const float* __restrict__ x, const float* __restrict__ wqkv,
    u16* __restrict__ Q, u16* __restrict__ Kk, u16* __restrict__ VT) {
  const int og = blockIdx.x;   // 0..47
  const int b  = blockIdx.y;
  const int tid = threadIdx.x;
  const int o0 = og * 16;

  float acc[4][16];
#pragma unroll
  for (int p = 0; p < 4; ++p)
#pragma unroll
    for (int o = 0; o < 16; ++o) acc[p][o] = 0.f;

  const float* xb = x + (size_t)b * C * NPIX;
  for (int c = 0; c < C; ++c) {
    float xv[4];
#pragma unroll
    for (int p = 0; p < 4; ++p)
      xv[p] = xb[c * NPIX + p * 256 + tid];
#pragma unroll
    for (int o = 0; o < 16; ++o) {
      float wv = wqkv[(o0 + o) * C + c];   // block-uniform -> scalar load
#pragma unroll
      for (int p = 0; p < 4; ++p) acc[p][o] += xv[p] * wv;
    }
  }

  const int part = og >> 4;            // 0=q 1=k 2=v
  const int ch0  = (og & 15) * 16;
  const int hh   = ch0 >> 5;
  const int dd0  = ch0 & 31;           // 0 or 16
  const int bh   = b * HEADS + hh;

  if (part < 2) {
    u16* dst = (part == 0 ? Q : Kk) + ((size_t)bh * NPIX) * D + dd0;
#pragma unroll
    for (int p = 0; p < 4; ++p) {
      const int pix = p * 256 + tid;
      uint pk[8];
#pragma unroll
      for (int q2 = 0; q2 < 8; ++q2)
        pk[q2] = (uint)f2bf(acc[p][2 * q2]) | ((uint)f2bf(acc[p][2 * q2 + 1]) << 16);
      uint4* dp = (uint4*)(dst + (size_t)pix * D);
      dp[0] = make_uint4(pk[0], pk[1], pk[2], pk[3]);
      dp[1] = make_uint4(pk[4], pk[5], pk[6], pk[7]);
    }
  } else {
    // transposed store: VT[bh][d][pix] (coalesced u16 across lanes)
#pragma unroll
    for (int o = 0; o < 16; ++o) {
      u16* vrow = VT + ((size_t)bh * D + (dd0 + o)) * NPIX;
#pragma unroll
      for (int p = 0; p < 4; ++p)
        vrow[p * 256 + tid] = f2bf(acc[p][o]);
    }
  }
}

// ---------------------------------------------------------------------------
// K1b: diag_vec[b][c] = (SCALE/8) * sum_h sum_t q[b,h,33t,c]*k[b,h,33t,c]
// ---------------------------------------------------------------------------
__global__ __launch_bounds__(256) void k_diag(
    const uint* __restrict__ Q, const uint* __restrict__ Kk,
    float* __restrict__ diagv) {
  const int b = blockIdx.x, tid = threadIdx.x;
  const int hh = tid >> 5, dd = tid & 31;
  const uint* qb = Q + (size_t)(b * HEADS + hh) * NPIX * (D / 2);
  const uint* kb = Kk + (size_t)(b * HEADS + hh) * NPIX * (D / 2);
  float s = 0.f;
#pragma unroll 4
  for (int t = 0; t < 32; ++t) {
    uint qu = qb[t * 33 * (D / 2) + dd / 2];
    uint ku = kb[t * 33 * (D / 2) + dd / 2];
    float qv = (dd & 1) ? bf_hi(qu) : bf_lo(qu);
    float kv = (dd & 1) ? bf_hi(ku) : bf_lo(ku);
    s += qv * kv;
  }
  __shared__ float red[256];
  red[tid] = s;
  __syncthreads();
  if (tid < 32) {
    float v = 0.f;
#pragma unroll
    for (int h8 = 0; h8 < 8; ++h8) v += red[h8 * 32 + tid];
    diagv[b * 32 + tid] = v * (SCALE / 8.f);
  }
}

// ---------------------------------------------------------------------------
// K1c: colsum[bh][d] = sum_j VT[bh][d][j]  (row sums of VT -> contiguous)
// ---------------------------------------------------------------------------
__global__ __launch_bounds__(256) void k_colsum(
    const u16* __restrict__ VT, float* __restrict__ colsum) {
  const int bh = blockIdx.x, tid = threadIdx.x;
  const int dd = tid >> 3, sl = tid & 7;
  const uint* row = (const uint*)(VT + ((size_t)bh * D + dd) * NPIX) + sl * 64;
  float s = 0.f;
#pragma unroll 8
  for (int j = 0; j < 64; ++j) {
    uint u = row[j];
    s += bf_lo(u) + bf_hi(u);
  }
  __shared__ float red[256];
  red[tid] = s;
  __syncthreads();
  if (tid < 32) {
    float v = 0.f;
#pragma unroll
    for (int g = 0; g < 8; ++g) v += red[tid * 8 + g];
    colsum[bh * D + tid] = v;
  }
}

// ---------------------------------------------------------------------------
// K2: MFMA flash attention (no-max softmax, verified numerically in R5).
// Grid (8 qchunks, 64 bh), block 256 = 4 waves; wave owns 32 q-rows.
// Per 64-j iter: 8 MFMA QK^T -> exp (fp32) -> P via LDS (C->A layout) ->
// 8 MFMA PV with B-frags from VT. l accumulated per-lane, reduced at end.
// ---------------------------------------------------------------------------
__global__ __launch_bounds__(256) void k_attn(
    const u16* __restrict__ Q, const u16* __restrict__ Kk,
    const u16* __restrict__ VT, const float* __restrict__ diagv,
    const float* __restrict__ colsum, u16* __restrict__ AO) {
  const int qc = blockIdx.x;           // 0..7
  const int bh = blockIdx.y;           // 0..63
  const int b = bh >> 3, hh = bh & 7;
  const int wv = threadIdx.x >> 6, lane = threadIdx.x & 63;
  const int quad = lane >> 4, l15 = lane & 15;
  const int i0 = qc * 128 + wv * 32;

  __shared__ float Pws_all[4][32 * PPITCH];   // 34.8 KB
  float* Pws = Pws_all[wv];

  const u16* Qb  = Q  + (size_t)bh * NPIX * D;
  const u16* Kb  = Kk + (size_t)bh * NPIX * D;
  const u16* VTb = VT + (size_t)bh * D * NPIX;

  // resident Q A-frags: A[m=l15][k=quad*8+jj]
  bf16x8 qfrag[2];
#pragma unroll
  for (int mt = 0; mt < 2; ++mt)
    qfrag[mt] = *(const bf16x8*)(Qb + (size_t)(i0 + mt * 16 + l15) * D + quad * 8);

  f32x4 oacc[2][2];                    // [mt][nt(d)]
#pragma unroll
  for (int mt = 0; mt < 2; ++mt)
#pragma unroll
    for (int nt = 0; nt < 2; ++nt) oacc[mt][nt] = (f32x4){0.f, 0.f, 0.f, 0.f};
  float lacc[2][4] = {};

  for (int jb = 0; jb < NPIX; jb += 64) {
    // ---- S = Q K^T (8 MFMA) ----
    f32x4 st[2][4];
#pragma unroll
    for (int jt = 0; jt < 4; ++jt) {
      bf16x8 kfrag = *(const bf16x8*)(Kb + (size_t)(jb + jt * 16 + l15) * D + quad * 8);
#pragma unroll
      for (int mt = 0; mt < 2; ++mt)
        st[mt][jt] = __builtin_amdgcn_mfma_f32_16x16x32_bf16(
            qfrag[mt], kfrag, (f32x4){0.f, 0.f, 0.f, 0.f}, 0, 0, 0);
    }
    // ---- exp + l-accumulate + P -> LDS (C-layout write) ----
#pragma unroll
    for (int mt = 0; mt < 2; ++mt)
#pragma unroll
      for (int jt = 0; jt < 4; ++jt)
#pragma unroll
        for (int r = 0; r < 4; ++r) {
          float s = st[mt][jt][r] * (SCALE * LOG2E);
          s = fminf(fmaxf(s, -80.f), 80.f);
          float pv = exp2f(s);
          lacc[mt][r] += pv;
          Pws[(mt * 16 + quad * 4 + r) * PPITCH + jt * 16 + l15] = pv;
        }
    __syncthreads();
    // ---- PV: read P in A-layout, pack bf16, 8 MFMA with VT B-frags ----
#pragma unroll
    for (int kt = 0; kt < 2; ++kt) {
      bf16x8 pfrag[2];
#pragma unroll
      for (int mt = 0; mt < 2; ++mt) {
        const float* src = &Pws[(mt * 16 + l15) * PPITCH + kt * 32 + quad * 8];
        float4 a = *(const float4*)(src);
        float4 bq = *(const float4*)(src + 4);
        bf16x8 f;
        f[0] = (short)f2bf(a.x);  f[1] = (short)f2bf(a.y);
        f[2] = (short)f2bf(a.z);  f[3] = (short)f2bf(a.w);
        f[4] = (short)f2bf(bq.x); f[5] = (short)f2bf(bq.y);
        f[6] = (short)f2bf(bq.z); f[7] = (short)f2bf(bq.w);
        pfrag[mt] = f;
      }
#pragma unroll
      for (int nt = 0; nt < 2; ++nt) {
        bf16x8 vfrag = *(const bf16x8*)(VTb + (size_t)(nt * 16 + l15) * NPIX +
                                        jb + kt * 32 + quad * 8);
#pragma unroll
        for (int mt = 0; mt < 2; ++mt)
          oacc[mt][nt] = __builtin_amdgcn_mfma_f32_16x16x32_bf16(
              pfrag[mt], vfrag, oacc[mt][nt], 0, 0, 0);
      }
    }
    __syncthreads();
  }

  // ---- reduce l across the 16 col-classes (within quad) ----
#pragma unroll
  for (int mt = 0; mt < 2; ++mt)
#pragma unroll
    for (int r = 0; r < 4; ++r) {
      float v = lacc[mt][r];
      v += __shfl_xor(v, 1, 16);
      v += __shfl_xor(v, 2, 16);
      v += __shfl_xor(v, 4, 16);
      v += __shfl_xor(v, 8, 16);
      lacc[mt][r] = v;
    }

  // ---- epilogue: normalize, diag term, store AO[b][ch][pix] bf16 ----
  const bool do_diag = (qc == 0) && (wv == 0);
#pragma unroll
  for (int mt = 0; mt < 2; ++mt) {
    const int ibase = i0 + mt * 16 + quad * 4;
#pragma unroll
    for (int nt = 0; nt < 2; ++nt) {
      const int d = nt * 16 + l15;
      const int ch = hh * 32 + d;
      float cs = do_diag ? colsum[bh * D + d] : 0.f;
      u16 w[4];
#pragma unroll
      for (int r = 0; r < 4; ++r) {
        float o = oacc[mt][nt][r] / lacc[mt][r];
        if (do_diag)
          o += 0.3f * diagv[b * 32 + (mt * 16 + quad * 4 + r)] * cs;
        w[r] = f2bf(o);
      }
      uint2 pk = make_uint2((uint)w[0] | ((uint)w[1] << 16),
                            (uint)w[2] | ((uint)w[3] << 16));
      *(uint2*)(AO + ((size_t)b * C + ch) * NPIX + ibase) = pk;
    }
  }
}

// ---------------------------------------------------------------------------
// K3: gate. One block per (b, row h); 16 distinct gate values per row.
// ---------------------------------------------------------------------------
__global__ __launch_bounds__(256) void k_gate(
    const float* __restrict__ x,
    const float* __restrict__ wg1, const float* __restrict__ bg1,
    const float* __restrict__ wg2, const float* __restrict__ bg2,
    float* __restrict__ gate) {
  const int h = blockIdx.x, b = blockIdx.y, tid = threadIdx.x;
  __shared__ float pl[16 * 257];   // 16.4 KB
  __shared__ float gl[16 * 65];

  {  // stage pooled: thread = channel c
    const int c = tid;
    const float* row = x + ((size_t)(b * C + c) * NPIX + h * 32);
    float v[32];
#pragma unroll
    for (int m = 0; m < 32; ++m) v[m] = row[m];
#pragma unroll
    for (int k = 0; k < 16; ++k) pl[k * 257 + c] = fabsf(v[k] - v[31 - k]);
  }
  __syncthreads();

  const int o16 = tid >> 4, k = tid & 15;
#pragma unroll 1
  for (int p = 0; p < 4; ++p) {
    const int o = p * 16 + o16;
    float a = bg1[o];
    const float* wr = wg1 + o * C;
    for (int c = 0; c < C; ++c)
      a += wr[c] * pl[k * 257 + c];
    gl[k * 65 + o] = 0.5f * a * (1.f + erff(a * 0.70710678118654752f));
  }
  __syncthreads();

  if (tid < 16) {
    float s = bg2[0];
    for (int o = 0; o < 64; ++o)
      s += wg2[o] * gl[tid * 65 + o];
    gate[(b * 32 + h) * 16 + tid] = 1.f / (1.f + expf(-s));
  }
}

// ---------------------------------------------------------------------------
// K4: epilogue projection with gate. OUTPUT FP32.
// ---------------------------------------------------------------------------
__global__ __launch_bounds__(256) void k_out(
    const u16* __restrict__ AO, const float* __restrict__ wout,
    const float* __restrict__ bout, const float* __restrict__ gate,
    float* __restrict__ out) {
  const int pc = blockIdx.x, og = blockIdx.y, b = blockIdx.z;
  const int tid = threadIdx.x;
  const int pix = pc * 256 + tid;

  float acc[16];
#pragma unroll
  for (int o = 0; o < 16; ++o) acc[o] = 0.f;

  const u16* ab = AO + (size_t)b * C * NPIX + pix;
  for (int c = 0; c < C; ++c) {
    float av = __uint_as_float(((uint)ab[(size_t)c * NPIX]) << 16);
#pragma unroll
    for (int o = 0; o < 16; ++o)
      acc[o] += wout[(og * 16 + o) * C + c] * av;
  }

  const float gf = 1.f + gate[(b * 32 + (pix >> 5)) * 16 + ((pix & 31) >> 1)];
#pragma unroll
  for (int o = 0; o < 16; ++o) {
    float r = acc[o] * gf + bout[og * 16 + o];
    out[((size_t)b * C + og * 16 + o) * NPIX + pix] = r;
  }
}

// ---------------------------------------------------------------------------
extern "C" void kernel_launch(void* const* d_in, const int* in_sizes, int n_in,
                              void* d_out, int out_size, void* d_ws, size_t ws_size,
                              hipStream_t stream) {
  const float* x    = (const float*)d_in[0];
  const float* wqkv = (const float*)d_in[1];
  const float* wout = (const float*)d_in[2];
  const float* bout = (const float*)d_in[3];
  const float* wg1  = (const float*)d_in[4];
  const float* bg1  = (const float*)d_in[5];
  const float* wg2  = (const float*)d_in[6];
  const float* bg2  = (const float*)d_in[7];
  float* out = (float*)d_out;   // fp32 output

  // workspace (~16.05 MB): Q,K,VT bf16 4MB each; AO bf16 4MB; fp32 tails.
  const size_t SZ = (size_t)B * HEADS * NPIX * D;  // elements per buffer
  u16* Q  = (u16*)d_ws;
  u16* Kq = Q + SZ;
  u16* VT = Kq + SZ;
  u16* AO = VT + SZ;
  float* DIAG = (float*)(AO + SZ);
  float* COL  = DIAG + 256;
  float* GATE = COL + 2048;

  hipLaunchKernelGGL(k_qkv, dim3(48, B), dim3(256), 0, stream, x, wqkv, Q, Kq, VT);
  hipLaunchKernelGGL(k_diag, dim3(B), dim3(256), 0, stream,
                     (const uint*)Q, (const uint*)Kq, DIAG);
  hipLaunchKernelGGL(k_colsum, dim3(B * HEADS), dim3(256), 0, stream, VT, COL);
  hipLaunchKernelGGL(k_attn, dim3(8, 64), dim3(256), 0, stream,
                     Q, Kq, VT, DIAG, COL, AO);
  hipLaunchKernelGGL(k_gate, dim3(32, B), dim3(256), 0, stream,
                     x, wg1, bg1, wg2, bg2, GATE);
  hipLaunchKernelGGL(k_out, dim3(4, 16, B), dim3(256), 0, stream,
                     AO, wout, bout, GATE, out);
}

// Round 7
// 201.480 us; speedup vs baseline: 5.1020x; 1.5887x over previous
//
#include <hip/hip_runtime.h>
#include <hip/hip_bf16.h>
#include <math.h>

#define B 8
#define C 256
#define HEADS 8
#define D 32
#define NPIX 1024
#define OC 768
#define SCALE 0.17677669529663687f   // 1/sqrt(32)
#define LOG2E 1.4426950408889634f
#define PPITCH 68                    // fp32 LDS pitch for P (16B-aligned rows)

typedef unsigned int uint;
typedef unsigned short u16;
typedef __attribute__((ext_vector_type(8))) short bf16x8;
typedef __attribute__((ext_vector_type(4))) float f32x4;

static __device__ inline u16 f2bf(float f) {   // RNE f32->bf16
  uint u = __float_as_uint(f);
  return (u16)((u + 0x7fffu + ((u >> 16) & 1u)) >> 16);
}
static __device__ inline float bf_lo(uint u) { return __uint_as_float(u << 16); }
static __device__ inline float bf_hi(uint u) { return __uint_as_float(u & 0xffff0000u); }

// ---------------------------------------------------------------------------
// P0a: convert wqkv (768x256) and wout (256x256) fp32 -> bf16.
// 256 blocks x 256 thr x 4 elem. Blocks [0,192): wqkv; [192,256): wout.
// ---------------------------------------------------------------------------
__global__ __launch_bounds__(256) void k_prep_w(
    const float* __restrict__ wqkv, const float* __restrict__ wout,
    u16* __restrict__ WQ, u16* __restrict__ WO) {
  const int bid = blockIdx.x, t = threadIdx.x;
  const float* src;
  u16* dst;
  int base;
  if (bid < 192) { src = wqkv; dst = WQ; base = bid * 1024; }
  else           { src = wout; dst = WO; base = (bid - 192) * 1024; }
  float4 v = *(const float4*)(src + base + t * 4);
  uint2 pk = make_uint2((uint)f2bf(v.x) | ((uint)f2bf(v.y) << 16),
                        (uint)f2bf(v.z) | ((uint)f2bf(v.w) << 16));
  *(uint2*)(dst + base + t * 4) = pk;
}

// ---------------------------------------------------------------------------
// P0b: transpose-convert x[b][c][pix] fp32 -> XT[b][pix][c] bf16.
// 64x64 LDS tile per block. Grid (16 pix-tiles, 4 c-tiles, 8 b).
// ---------------------------------------------------------------------------
__global__ __launch_bounds__(256) void k_prep_x(
    const float* __restrict__ x, u16* __restrict__ XT) {
  const int pt = blockIdx.x, ct = blockIdx.y, b = blockIdx.z;
  __shared__ u16 tile[64][65];
  const int t = threadIdx.x;
  {
    const int px = t & 63, cq = t >> 6;
    const float* xb = x + ((size_t)(b * C + ct * 64)) * NPIX + pt * 64;
#pragma unroll
    for (int m = 0; m < 16; ++m) {
      const int c = cq * 16 + m;
      tile[c][px] = f2bf(xb[(size_t)c * NPIX + px]);
    }
  }
  __syncthreads();
  {
    const int cc = t & 63, pq = t >> 6;
    u16* dst = XT + ((size_t)(b * NPIX + pt * 64)) * C + ct * 64;
#pragma unroll
    for (int m = 0; m < 16; ++m) {
      const int pix = pq * 16 + m;
      dst[(size_t)pix * C + cc] = tile[cc][pix];
    }
  }
}

// ---------------------------------------------------------------------------
// K1: QKV GEMM via MFMA. D[o][pix] = W[o][c] . XT[pix][c]^T.
// Grid (12 o-blocks of 64, 8 pix-blocks of 128, 8 b), 4 waves.
// Wave: 16 o x 128 pix, K=256 (8 kc). part = ob>>2: 0=Q 1=K 2=V(T).
// ---------------------------------------------------------------------------
__global__ __launch_bounds__(256) void k_qkv_mfma(
    const u16* __restrict__ XT, const u16* __restrict__ WQ,
    u16* __restrict__ Q, u16* __restrict__ Kk, u16* __restrict__ VT) {
  const int ob = blockIdx.x, pb = blockIdx.y, b = blockIdx.z;
  const int wv = threadIdx.x >> 6, lane = threadIdx.x & 63;
  const int quad = lane >> 4, l15 = lane & 15;
  const int part = ob >> 2;
  const int odl = (ob & 3) * 64 + wv * 16;   // channel within the 256-part
  const int hh = odl >> 5, d0 = odl & 31;
  const int bh = b * HEADS + hh;
  const int pix0 = pb * 128;

  const u16* arow = WQ + (size_t)(ob * 64 + wv * 16 + l15) * C;
  bf16x8 af[8];
#pragma unroll
  for (int kc = 0; kc < 8; ++kc)
    af[kc] = *(const bf16x8*)(arow + kc * 32 + quad * 8);

  const u16* xb = XT + (size_t)(b * NPIX + pix0) * C;
  f32x4 acc[8];
#pragma unroll
  for (int nt = 0; nt < 8; ++nt) acc[nt] = (f32x4){0.f, 0.f, 0.f, 0.f};

  for (int kc = 0; kc < 8; ++kc) {
#pragma unroll
    for (int nt = 0; nt < 8; ++nt) {
      bf16x8 bfr = *(const bf16x8*)(xb + (size_t)(nt * 16 + l15) * C +
                                    kc * 32 + quad * 8);
      acc[nt] = __builtin_amdgcn_mfma_f32_16x16x32_bf16(af[kc], bfr, acc[nt], 0, 0, 0);
    }
  }

  if (part < 2) {
    u16* dst = (part == 0 ? Q : Kk) + (size_t)bh * NPIX * D;
#pragma unroll
    for (int nt = 0; nt < 8; ++nt) {
      const int pix = pix0 + nt * 16 + l15;
      uint2 pk = make_uint2(
          (uint)f2bf(acc[nt][0]) | ((uint)f2bf(acc[nt][1]) << 16),
          (uint)f2bf(acc[nt][2]) | ((uint)f2bf(acc[nt][3]) << 16));
      *(uint2*)(dst + (size_t)pix * D + d0 + 4 * quad) = pk;
    }
  } else {
#pragma unroll
    for (int nt = 0; nt < 8; ++nt) {
      const int pix = pix0 + nt * 16 + l15;
#pragma unroll
      for (int r = 0; r < 4; ++r) {
        const int d = d0 + 4 * quad + r;
        VT[((size_t)bh * D + d) * NPIX + pix] = f2bf(acc[nt][r]);
      }
    }
  }
}

// ---------------------------------------------------------------------------
// K1b: diag_vec[b][c] = (SCALE/8) * sum_h sum_t q[b,h,33t,c]*k[b,h,33t,c]
// ---------------------------------------------------------------------------
__global__ __launch_bounds__(256) void k_diag(
    const uint* __restrict__ Q, const uint* __restrict__ Kk,
    float* __restrict__ diagv) {
  const int b = blockIdx.x, tid = threadIdx.x;
  const int hh = tid >> 5, dd = tid & 31;
  const uint* qb = Q + (size_t)(b * HEADS + hh) * NPIX * (D / 2);
  const uint* kb = Kk + (size_t)(b * HEADS + hh) * NPIX * (D / 2);
  float s = 0.f;
#pragma unroll 4
  for (int t = 0; t < 32; ++t) {
    uint qu = qb[t * 33 * (D / 2) + dd / 2];
    uint ku = kb[t * 33 * (D / 2) + dd / 2];
    float qv = (dd & 1) ? bf_hi(qu) : bf_lo(qu);
    float kv = (dd & 1) ? bf_hi(ku) : bf_lo(ku);
    s += qv * kv;
  }
  __shared__ float red[256];
  red[tid] = s;
  __syncthreads();
  if (tid < 32) {
    float v = 0.f;
#pragma unroll
    for (int h8 = 0; h8 < 8; ++h8) v += red[h8 * 32 + tid];
    diagv[b * 32 + tid] = v * (SCALE / 8.f);
  }
}

// ---------------------------------------------------------------------------
// K1c: colsum[bh][d] = sum_j VT[bh][d][j]
// ---------------------------------------------------------------------------
__global__ __launch_bounds__(256) void k_colsum(
    const u16* __restrict__ VT, float* __restrict__ colsum) {
  const int bh = blockIdx.x, tid = threadIdx.x;
  const int dd = tid >> 3, sl = tid & 7;
  const uint* row = (const uint*)(VT + ((size_t)bh * D + dd) * NPIX) + sl * 64;
  float s = 0.f;
#pragma unroll 8
  for (int j = 0; j < 64; ++j) {
    uint u = row[j];
    s += bf_lo(u) + bf_hi(u);
  }
  __shared__ float red[256];
  red[tid] = s;
  __syncthreads();
  if (tid < 32) {
    float v = 0.f;
#pragma unroll
    for (int g = 0; g < 8; ++g) v += red[tid * 8 + g];
    colsum[bh * D + tid] = v;
  }
}

// ---------------------------------------------------------------------------
// K2: MFMA flash attention (no-max softmax). Writes AOT[b][pix][ch] bf16.
// ---------------------------------------------------------------------------
__global__ __launch_bounds__(256) void k_attn(
    const u16* __restrict__ Q, const u16* __restrict__ Kk,
    const u16* __restrict__ VT, const float* __restrict__ diagv,
    const float* __restrict__ colsum, u16* __restrict__ AOT) {
  const int qc = blockIdx.x;           // 0..7
  const int bh = blockIdx.y;           // 0..63
  const int b = bh >> 3, hh = bh & 7;
  const int wv = threadIdx.x >> 6, lane = threadIdx.x & 63;
  const int quad = lane >> 4, l15 = lane & 15;
  const int i0 = qc * 128 + wv * 32;

  __shared__ float Pws_all[4][32 * PPITCH];   // 34.8 KB
  float* Pws = Pws_all[wv];

  const u16* Qb  = Q  + (size_t)bh * NPIX * D;
  const u16* Kb  = Kk + (size_t)bh * NPIX * D;
  const u16* VTb = VT + (size_t)bh * D * NPIX;

  bf16x8 qfrag[2];
#pragma unroll
  for (int mt = 0; mt < 2; ++mt)
    qfrag[mt] = *(const bf16x8*)(Qb + (size_t)(i0 + mt * 16 + l15) * D + quad * 8);

  f32x4 oacc[2][2];
#pragma unroll
  for (int mt = 0; mt < 2; ++mt)
#pragma unroll
    for (int nt = 0; nt < 2; ++nt) oacc[mt][nt] = (f32x4){0.f, 0.f, 0.f, 0.f};
  float lacc[2][4] = {};

  for (int jb = 0; jb < NPIX; jb += 64) {
    f32x4 st[2][4];
#pragma unroll
    for (int jt = 0; jt < 4; ++jt) {
      bf16x8 kfrag = *(const bf16x8*)(Kb + (size_t)(jb + jt * 16 + l15) * D + quad * 8);
#pragma unroll
      for (int mt = 0; mt < 2; ++mt)
        st[mt][jt] = __builtin_amdgcn_mfma_f32_16x16x32_bf16(
            qfrag[mt], kfrag, (f32x4){0.f, 0.f, 0.f, 0.f}, 0, 0, 0);
    }
#pragma unroll
    for (int mt = 0; mt < 2; ++mt)
#pragma unroll
      for (int jt = 0; jt < 4; ++jt)
#pragma unroll
        for (int r = 0; r < 4; ++r) {
          float s = st[mt][jt][r] * (SCALE * LOG2E);
          s = fminf(fmaxf(s, -80.f), 80.f);
          float pv = exp2f(s);
          lacc[mt][r] += pv;
          Pws[(mt * 16 + quad * 4 + r) * PPITCH + jt * 16 + l15] = pv;
        }
    __syncthreads();
#pragma unroll
    for (int kt = 0; kt < 2; ++kt) {
      bf16x8 pfrag[2];
#pragma unroll
      for (int mt = 0; mt < 2; ++mt) {
        const float* src = &Pws[(mt * 16 + l15) * PPITCH + kt * 32 + quad * 8];
        float4 a = *(const float4*)(src);
        float4 bq = *(const float4*)(src + 4);
        bf16x8 f;
        f[0] = (short)f2bf(a.x);  f[1] = (short)f2bf(a.y);
        f[2] = (short)f2bf(a.z);  f[3] = (short)f2bf(a.w);
        f[4] = (short)f2bf(bq.x); f[5] = (short)f2bf(bq.y);
        f[6] = (short)f2bf(bq.z); f[7] = (short)f2bf(bq.w);
        pfrag[mt] = f;
      }
#pragma unroll
      for (int nt = 0; nt < 2; ++nt) {
        bf16x8 vfrag = *(const bf16x8*)(VTb + (size_t)(nt * 16 + l15) * NPIX +
                                        jb + kt * 32 + quad * 8);
#pragma unroll
        for (int mt = 0; mt < 2; ++mt)
          oacc[mt][nt] = __builtin_amdgcn_mfma_f32_16x16x32_bf16(
              pfrag[mt], vfrag, oacc[mt][nt], 0, 0, 0);
      }
    }
    __syncthreads();
  }

#pragma unroll
  for (int mt = 0; mt < 2; ++mt)
#pragma unroll
    for (int r = 0; r < 4; ++r) {
      float v = lacc[mt][r];
      v += __shfl_xor(v, 1, 16);
      v += __shfl_xor(v, 2, 16);
      v += __shfl_xor(v, 4, 16);
      v += __shfl_xor(v, 8, 16);
      lacc[mt][r] = v;
    }

  const bool do_diag = (qc == 0) && (wv == 0);
#pragma unroll
  for (int mt = 0; mt < 2; ++mt) {
    const int ibase = i0 + mt * 16 + quad * 4;
#pragma unroll
    for (int nt = 0; nt < 2; ++nt) {
      const int dch = hh * 32 + nt * 16 + l15;
      float cs = do_diag ? colsum[bh * D + (nt * 16 + l15)] : 0.f;
#pragma unroll
      for (int r = 0; r < 4; ++r) {
        float o = oacc[mt][nt][r] / lacc[mt][r];
        if (do_diag)
          o += 0.3f * diagv[b * 32 + (mt * 16 + quad * 4 + r)] * cs;
        AOT[((size_t)b * NPIX + ibase + r) * C + dch] = f2bf(o);
      }
    }
  }
}

// ---------------------------------------------------------------------------
// K3: gate. One block per (b, row h); 16 distinct gate values per row.
// ---------------------------------------------------------------------------
__global__ __launch_bounds__(256) void k_gate(
    const float* __restrict__ x,
    const float* __restrict__ wg1, const float* __restrict__ bg1,
    const float* __restrict__ wg2, const float* __restrict__ bg2,
    float* __restrict__ gate) {
  const int h = blockIdx.x, b = blockIdx.y, tid = threadIdx.x;
  __shared__ float pl[16 * 257];
  __shared__ float gl[16 * 65];

  {
    const int c = tid;
    const float* row = x + ((size_t)(b * C + c) * NPIX + h * 32);
    float v[32];
#pragma unroll
    for (int m = 0; m < 32; ++m) v[m] = row[m];
#pragma unroll
    for (int k = 0; k < 16; ++k) pl[k * 257 + c] = fabsf(v[k] - v[31 - k]);
  }
  __syncthreads();

  const int o16 = tid >> 4, k = tid & 15;
#pragma unroll 1
  for (int p = 0; p < 4; ++p) {
    const int o = p * 16 + o16;
    float a = bg1[o];
    const float* wr = wg1 + o * C;
    for (int c = 0; c < C; ++c)
      a += wr[c] * pl[k * 257 + c];
    gl[k * 65 + o] = 0.5f * a * (1.f + erff(a * 0.70710678118654752f));
  }
  __syncthreads();

  if (tid < 16) {
    float s = bg2[0];
    for (int o = 0; o < 64; ++o)
      s += wg2[o] * gl[tid * 65 + o];
    gate[(b * 32 + h) * 16 + tid] = 1.f / (1.f + expf(-s));
  }
}

// ---------------------------------------------------------------------------
// K4: output GEMM via MFMA, gate+bias fused. out fp32 [b][o][pix].
// Grid (4 o-blocks of 64, 8 pix-blocks of 128, 8 b), 4 waves.
// ---------------------------------------------------------------------------
__global__ __launch_bounds__(256) void k_out_mfma(
    const u16* __restrict__ AOT, const u16* __restrict__ WO,
    const float* __restrict__ bout, const float* __restrict__ gate,
    float* __restrict__ out) {
  const int ob = blockIdx.x, pb = blockIdx.y, b = blockIdx.z;
  const int wv = threadIdx.x >> 6, lane = threadIdx.x & 63;
  const int quad = lane >> 4, l15 = lane & 15;
  const int o0 = ob * 64 + wv * 16;
  const int pix0 = pb * 128;

  const u16* arow = WO + (size_t)(o0 + l15) * C;
  bf16x8 af[8];
#pragma unroll
  for (int kc = 0; kc < 8; ++kc)
    af[kc] = *(const bf16x8*)(arow + kc * 32 + quad * 8);

  const u16* ab = AOT + (size_t)(b * NPIX + pix0) * C;
  f32x4 acc[8];
#pragma unroll
  for (int nt = 0; nt < 8; ++nt) acc[nt] = (f32x4){0.f, 0.f, 0.f, 0.f};

  for (int kc = 0; kc < 8; ++kc) {
#pragma unroll
    for (int nt = 0; nt < 8; ++nt) {
      bf16x8 bfr = *(const bf16x8*)(ab + (size_t)(nt * 16 + l15) * C +
                                    kc * 32 + quad * 8);
      acc[nt] = __builtin_amdgcn_mfma_f32_16x16x32_bf16(af[kc], bfr, acc[nt], 0, 0, 0);
    }
  }

#pragma unroll
  for (int nt = 0; nt < 8; ++nt) {
    const int pix = pix0 + nt * 16 + l15;
    const float gf = 1.f + gate[(b * 32 + (pix >> 5)) * 16 + ((pix & 31) >> 1)];
#pragma unroll
    for (int r = 0; r < 4; ++r) {
      const int o = o0 + 4 * quad + r;
      out[((size_t)b * C + o) * NPIX + pix] = acc[nt][r] * gf + bout[o];
    }
  }
}

// ---------------------------------------------------------------------------
extern "C" void kernel_launch(void* const* d_in, const int* in_sizes, int n_in,
                              void* d_out, int out_size, void* d_ws, size_t ws_size,
                              hipStream_t stream) {
  const float* x    = (const float*)d_in[0];
  const float* wqkv = (const float*)d_in[1];
  const float* wout = (const float*)d_in[2];
  const float* bout = (const float*)d_in[3];
  const float* wg1  = (const float*)d_in[4];
  const float* bg1  = (const float*)d_in[5];
  const float* wg2  = (const float*)d_in[6];
  const float* bg2  = (const float*)d_in[7];
  float* out = (float*)d_out;

  // workspace (~17.3 MB):
  //  XT (bf16 2M el, 4MB) -- reused as AOT after k_qkv_mfma consumes it
  //  WQ (196608) WO (65536) | Q, K, VT (2M el each) | fp32 tails
  const size_t SZ = (size_t)B * HEADS * NPIX * D;   // 2,097,152
  u16* XT = (u16*)d_ws;
  u16* WQ = XT + SZ;
  u16* WO = WQ + (size_t)OC * C;
  u16* Q  = WO + (size_t)C * C;
  u16* Kq = Q + SZ;
  u16* VT = Kq + SZ;
  float* DIAG = (float*)(VT + SZ);
  float* COL  = DIAG + 256;
  float* GATE = COL + 2048;
  u16* AOT = XT;   // alias: XT dead after k_qkv_mfma

  hipLaunchKernelGGL(k_prep_w, dim3(256), dim3(256), 0, stream, wqkv, wout, WQ, WO);
  hipLaunchKernelGGL(k_prep_x, dim3(16, 4, B), dim3(256), 0, stream, x, XT);
  hipLaunchKernelGGL(k_qkv_mfma, dim3(12, 8, B), dim3(256), 0, stream,
                     XT, WQ, Q, Kq, VT);
  hipLaunchKernelGGL(k_diag, dim3(B), dim3(256), 0, stream,
                     (const uint*)Q, (const uint*)Kq, DIAG);
  hipLaunchKernelGGL(k_colsum, dim3(B * HEADS), dim3(256), 0, stream, VT, COL);
  hipLaunchKernelGGL(k_attn, dim3(8, 64), dim3(256), 0, stream,
                     Q, Kq, VT, DIAG, COL, AOT);
  hipLaunchKernelGGL(k_gate, dim3(32, B), dim3(256), 0, stream,
                     x, wg1, bg1, wg2, bg2, GATE);
  hipLaunchKernelGGL(k_out_mfma, dim3(4, 8, B), dim3(256), 0, stream,
                     AOT, WO, bout, GATE, out);
}

// Round 8
// 183.323 us; speedup vs baseline: 5.6074x; 1.0990x over previous
//
#include <hip/hip_runtime.h>
#include <hip/hip_bf16.h>
#include <math.h>

#define B 8
#define C 256
#define HEADS 8
#define D 32
#define NPIX 1024
#define OC 768
#define SCALE 0.17677669529663687f   // 1/sqrt(32)
#define LOG2E 1.4426950408889634f
#define PPITCH 68                    // fp32 LDS pitch for P rows (16B-aligned)

typedef unsigned int uint;
typedef unsigned short u16;
typedef __attribute__((ext_vector_type(8))) short bf16x8;
typedef __attribute__((ext_vector_type(4))) float f32x4;

static __device__ inline u16 f2bf(float f) {   // RNE f32->bf16
  uint u = __float_as_uint(f);
  return (u16)((u + 0x7fffu + ((u >> 16) & 1u)) >> 16);
}
static __device__ inline float bf_lo(uint u) { return __uint_as_float(u << 16); }
static __device__ inline float bf_hi(uint u) { return __uint_as_float(u & 0xffff0000u); }

// ---------------------------------------------------------------------------
// P0: fused prep. Blocks [0,256): weights fp32->bf16 (wqkv then wout).
// Blocks [256,768): transpose-convert x[b][c][pix] -> XT[b][pix][c] bf16.
// ---------------------------------------------------------------------------
__global__ __launch_bounds__(256) void k_prep(
    const float* __restrict__ x, const float* __restrict__ wqkv,
    const float* __restrict__ wout,
    u16* __restrict__ WQ, u16* __restrict__ WO, u16* __restrict__ XT) {
  const int bid = blockIdx.x, t = threadIdx.x;
  __shared__ u16 tile[64][65];
  if (bid < 256) {
    const float* src;
    u16* dst;
    int base;
    if (bid < 192) { src = wqkv; dst = WQ; base = bid * 1024; }
    else           { src = wout; dst = WO; base = (bid - 192) * 1024; }
    float4 v = *(const float4*)(src + base + t * 4);
    uint2 pk = make_uint2((uint)f2bf(v.x) | ((uint)f2bf(v.y) << 16),
                          (uint)f2bf(v.z) | ((uint)f2bf(v.w) << 16));
    *(uint2*)(dst + base + t * 4) = pk;
    return;
  }
  const int id = bid - 256;
  const int pt = id & 15, ct = (id >> 4) & 3, b = id >> 6;
  {
    const int px = t & 63, cq = t >> 6;
    const float* xb = x + ((size_t)(b * C + ct * 64)) * NPIX + pt * 64;
#pragma unroll
    for (int m = 0; m < 16; ++m) {
      const int c = cq * 16 + m;
      tile[c][px] = f2bf(xb[(size_t)c * NPIX + px]);
    }
  }
  __syncthreads();
  {
    const int cc = t & 63, pq = t >> 6;
    u16* dst = XT + ((size_t)(b * NPIX + pt * 64)) * C + ct * 64;
#pragma unroll
    for (int m = 0; m < 16; ++m) {
      const int pix = pq * 16 + m;
      dst[(size_t)pix * C + cc] = tile[cc][pix];
    }
  }
}

// ---------------------------------------------------------------------------
// K1: QKV GEMM via MFMA. D[o][pix] = W[o][c] . XT[pix][c]^T.
// Grid (12 o-blocks of 64, 8 pix-blocks of 128, 8 b), 4 waves.
// ---------------------------------------------------------------------------
__global__ __launch_bounds__(256) void k_qkv_mfma(
    const u16* __restrict__ XT, const u16* __restrict__ WQ,
    u16* __restrict__ Q, u16* __restrict__ Kk, u16* __restrict__ VT) {
  const int ob = blockIdx.x, pb = blockIdx.y, b = blockIdx.z;
  const int wv = threadIdx.x >> 6, lane = threadIdx.x & 63;
  const int quad = lane >> 4, l15 = lane & 15;
  const int part = ob >> 2;
  const int odl = (ob & 3) * 64 + wv * 16;
  const int hh = odl >> 5, d0 = odl & 31;
  const int bh = b * HEADS + hh;
  const int pix0 = pb * 128;

  const u16* arow = WQ + (size_t)(ob * 64 + wv * 16 + l15) * C;
  bf16x8 af[8];
#pragma unroll
  for (int kc = 0; kc < 8; ++kc)
    af[kc] = *(const bf16x8*)(arow + kc * 32 + quad * 8);

  const u16* xb = XT + (size_t)(b * NPIX + pix0) * C;
  f32x4 acc[8];
#pragma unroll
  for (int nt = 0; nt < 8; ++nt) acc[nt] = (f32x4){0.f, 0.f, 0.f, 0.f};

  for (int kc = 0; kc < 8; ++kc) {
#pragma unroll
    for (int nt = 0; nt < 8; ++nt) {
      bf16x8 bfr = *(const bf16x8*)(xb + (size_t)(nt * 16 + l15) * C +
                                    kc * 32 + quad * 8);
      acc[nt] = __builtin_amdgcn_mfma_f32_16x16x32_bf16(af[kc], bfr, acc[nt], 0, 0, 0);
    }
  }

  if (part < 2) {
    u16* dst = (part == 0 ? Q : Kk) + (size_t)bh * NPIX * D;
#pragma unroll
    for (int nt = 0; nt < 8; ++nt) {
      const int pix = pix0 + nt * 16 + l15;
      uint2 pk = make_uint2(
          (uint)f2bf(acc[nt][0]) | ((uint)f2bf(acc[nt][1]) << 16),
          (uint)f2bf(acc[nt][2]) | ((uint)f2bf(acc[nt][3]) << 16));
      *(uint2*)(dst + (size_t)pix * D + d0 + 4 * quad) = pk;
    }
  } else {
#pragma unroll
    for (int nt = 0; nt < 8; ++nt) {
      const int pix = pix0 + nt * 16 + l15;
#pragma unroll
      for (int r = 0; r < 4; ++r) {
        const int d = d0 + 4 * quad + r;
        VT[((size_t)bh * D + d) * NPIX + pix] = f2bf(acc[nt][r]);
      }
    }
  }
}

// ---------------------------------------------------------------------------
// R: fused reductions. Blocks [0,8): diag_vec[b]. Blocks [8,72): colsum[bh].
// ---------------------------------------------------------------------------
__global__ __launch_bounds__(256) void k_red(
    const uint* __restrict__ Q, const uint* __restrict__ Kk,
    const u16* __restrict__ VT, float* __restrict__ diagv,
    float* __restrict__ colsum) {
  const int bid = blockIdx.x, tid = threadIdx.x;
  __shared__ float red[256];
  if (bid < 8) {
    const int b = bid;
    const int hh = tid >> 5, dd = tid & 31;
    const uint* qb = Q + (size_t)(b * HEADS + hh) * NPIX * (D / 2);
    const uint* kb = Kk + (size_t)(b * HEADS + hh) * NPIX * (D / 2);
    float s = 0.f;
#pragma unroll 4
    for (int t = 0; t < 32; ++t) {
      uint qu = qb[t * 33 * (D / 2) + dd / 2];
      uint ku = kb[t * 33 * (D / 2) + dd / 2];
      float qv = (dd & 1) ? bf_hi(qu) : bf_lo(qu);
      float kv = (dd & 1) ? bf_hi(ku) : bf_lo(ku);
      s += qv * kv;
    }
    red[tid] = s;
    __syncthreads();
    if (tid < 32) {
      float v = 0.f;
#pragma unroll
      for (int h8 = 0; h8 < 8; ++h8) v += red[h8 * 32 + tid];
      diagv[b * 32 + tid] = v * (SCALE / 8.f);
    }
  } else {
    const int bh = bid - 8;
    const int dd = tid >> 3, sl = tid & 7;
    const uint* row = (const uint*)(VT + ((size_t)bh * D + dd) * NPIX) + sl * 64;
    float s = 0.f;
#pragma unroll 8
    for (int j = 0; j < 64; ++j) {
      uint u = row[j];
      s += bf_lo(u) + bf_hi(u);
    }
    red[tid] = s;
    __syncthreads();
    if (tid < 32) {
      float v = 0.f;
#pragma unroll
      for (int g = 0; g < 8; ++g) v += red[tid * 8 + g];
      colsum[bh * D + tid] = v;
    }
  }
}

// ---------------------------------------------------------------------------
// K2: MFMA flash attention, barrier-free (wave-private P slice in LDS).
// Grid (16 qchunks of 64, 64 bh), 4 waves; wave owns 16 q-rows.
// ---------------------------------------------------------------------------
__global__ __launch_bounds__(256) void k_attn(
    const u16* __restrict__ Q, const u16* __restrict__ Kk,
    const u16* __restrict__ VT, const float* __restrict__ diagv,
    const float* __restrict__ colsum, u16* __restrict__ AOT) {
  const int qc = blockIdx.x;           // 0..15
  const int bh = blockIdx.y;           // 0..63
  const int b = bh >> 3, hh = bh & 7;
  const int wv = threadIdx.x >> 6, lane = threadIdx.x & 63;
  const int quad = lane >> 4, l15 = lane & 15;
  const int i0 = qc * 64 + wv * 16;

  __shared__ float Pws_all[4][16 * PPITCH];   // 17.4 KB, wave-private slices
  float* Pws = Pws_all[wv];

  const u16* Qb  = Q  + (size_t)bh * NPIX * D;
  const u16* Kb  = Kk + (size_t)bh * NPIX * D;
  const u16* VTb = VT + (size_t)bh * D * NPIX;

  bf16x8 qfrag = *(const bf16x8*)(Qb + (size_t)(i0 + l15) * D + quad * 8);

  f32x4 oacc[2];
  oacc[0] = (f32x4){0.f, 0.f, 0.f, 0.f};
  oacc[1] = (f32x4){0.f, 0.f, 0.f, 0.f};
  float lacc[4] = {};

  for (int jb = 0; jb < NPIX; jb += 64) {
    // prefetch V fragments for this j-block
    bf16x8 vfrag[2][2];
#pragma unroll
    for (int kt = 0; kt < 2; ++kt)
#pragma unroll
      for (int nt = 0; nt < 2; ++nt)
        vfrag[kt][nt] = *(const bf16x8*)(VTb + (size_t)(nt * 16 + l15) * NPIX +
                                         jb + kt * 32 + quad * 8);
    // S = Q K^T (4 MFMA), rows i=quad*4+r, cols j=jt*16+l15
    f32x4 st[4];
#pragma unroll
    for (int jt = 0; jt < 4; ++jt) {
      bf16x8 kfrag = *(const bf16x8*)(Kb + (size_t)(jb + jt * 16 + l15) * D + quad * 8);
      st[jt] = __builtin_amdgcn_mfma_f32_16x16x32_bf16(
          qfrag, kfrag, (f32x4){0.f, 0.f, 0.f, 0.f}, 0, 0, 0);
    }
    // exp + l-accumulate + P -> wave-private LDS (C-layout write)
#pragma unroll
    for (int jt = 0; jt < 4; ++jt)
#pragma unroll
      for (int r = 0; r < 4; ++r) {
        float s = fminf(st[jt][r] * (SCALE * LOG2E), 80.f);
        float pv = exp2f(s);
        lacc[r] += pv;
        Pws[(quad * 4 + r) * PPITCH + jt * 16 + l15] = pv;
      }
    __builtin_amdgcn_wave_barrier();   // scheduling fence; DS in-order per wave
    // PV: read P rows in A-layout, pack bf16, 4 MFMA
#pragma unroll
    for (int kt = 0; kt < 2; ++kt) {
      const float* src = &Pws[l15 * PPITCH + kt * 32 + quad * 8];
      float4 a = *(const float4*)(src);
      float4 bq = *(const float4*)(src + 4);
      bf16x8 f;
      f[0] = (short)f2bf(a.x);  f[1] = (short)f2bf(a.y);
      f[2] = (short)f2bf(a.z);  f[3] = (short)f2bf(a.w);
      f[4] = (short)f2bf(bq.x); f[5] = (short)f2bf(bq.y);
      f[6] = (short)f2bf(bq.z); f[7] = (short)f2bf(bq.w);
#pragma unroll
      for (int nt = 0; nt < 2; ++nt)
        oacc[nt] = __builtin_amdgcn_mfma_f32_16x16x32_bf16(
            f, vfrag[kt][nt], oacc[nt], 0, 0, 0);
    }
    __builtin_amdgcn_wave_barrier();
  }

  // reduce l across the 16 j-classes
#pragma unroll
  for (int r = 0; r < 4; ++r) {
    float v = lacc[r];
    v += __shfl_xor(v, 1, 16);
    v += __shfl_xor(v, 2, 16);
    v += __shfl_xor(v, 4, 16);
    v += __shfl_xor(v, 8, 16);
    lacc[r] = 1.f / v;
  }

  // epilogue: normalize, diag term (rows < 32), store AOT[b][pix][ch]
  const bool do_diag = (i0 < 32);
#pragma unroll
  for (int nt = 0; nt < 2; ++nt) {
    const int dch = hh * 32 + nt * 16 + l15;
    float cs = do_diag ? colsum[bh * D + (nt * 16 + l15)] : 0.f;
#pragma unroll
    for (int r = 0; r < 4; ++r) {
      const int irow = i0 + quad * 4 + r;
      float o = oacc[nt][r] * lacc[r];
      if (do_diag) o += 0.3f * diagv[b * 32 + irow] * cs;
      AOT[((size_t)b * NPIX + irow) * C + dch] = f2bf(o);
    }
  }
}

// ---------------------------------------------------------------------------
// K3: gate. One block per (b, row h); 16 distinct gate values per row.
// ---------------------------------------------------------------------------
__global__ __launch_bounds__(256) void k_gate(
    const float* __restrict__ x,
    const float* __restrict__ wg1, const float* __restrict__ bg1,
    const float* __restrict__ wg2, const float* __restrict__ bg2,
    float* __restrict__ gate) {
  const int h = blockIdx.x, b = blockIdx.y, tid = threadIdx.x;
  __shared__ float pl[16 * 257];
  __shared__ float gl[16 * 65];

  {
    const int c = tid;
    const float* row = x + ((size_t)(b * C + c) * NPIX + h * 32);
    float v[32];
#pragma unroll
    for (int m = 0; m < 32; ++m) v[m] = row[m];
#pragma unroll
    for (int k = 0; k < 16; ++k) pl[k * 257 + c] = fabsf(v[k] - v[31 - k]);
  }
  __syncthreads();

  const int o16 = tid >> 4, k = tid & 15;
#pragma unroll 1
  for (int p = 0; p < 4; ++p) {
    const int o = p * 16 + o16;
    const float* wr = wg1 + o * C;
    float a0 = 0.f, a1 = 0.f, a2 = 0.f, a3 = 0.f;
#pragma unroll 4
    for (int c = 0; c < C; c += 4) {
      a0 += wr[c]     * pl[k * 257 + c];
      a1 += wr[c + 1] * pl[k * 257 + c + 1];
      a2 += wr[c + 2] * pl[k * 257 + c + 2];
      a3 += wr[c + 3] * pl[k * 257 + c + 3];
    }
    float a = bg1[o] + ((a0 + a1) + (a2 + a3));
    gl[k * 65 + o] = 0.5f * a * (1.f + erff(a * 0.70710678118654752f));
  }
  __syncthreads();

  if (tid < 16) {
    float s = bg2[0];
    for (int o = 0; o < 64; ++o)
      s += wg2[o] * gl[tid * 65 + o];
    gate[(b * 32 + h) * 16 + tid] = 1.f / (1.f + expf(-s));
  }
}

// ---------------------------------------------------------------------------
// K4: output GEMM via MFMA, gate+bias fused. out fp32 [b][o][pix].
// ---------------------------------------------------------------------------
__global__ __launch_bounds__(256) void k_out_mfma(
    const u16* __restrict__ AOT, const u16* __restrict__ WO,
    const float* __restrict__ bout, const float* __restrict__ gate,
    float* __restrict__ out) {
  const int ob = blockIdx.x, pb = blockIdx.y, b = blockIdx.z;
  const int wv = threadIdx.x >> 6, lane = threadIdx.x & 63;
  const int quad = lane >> 4, l15 = lane & 15;
  const int o0 = ob * 64 + wv * 16;
  const int pix0 = pb * 128;

  const u16* arow = WO + (size_t)(o0 + l15) * C;
  bf16x8 af[8];
#pragma unroll
  for (int kc = 0; kc < 8; ++kc)
    af[kc] = *(const bf16x8*)(arow + kc * 32 + quad * 8);

  const u16* ab = AOT + (size_t)(b * NPIX + pix0) * C;
  f32x4 acc[8];
#pragma unroll
  for (int nt = 0; nt < 8; ++nt) acc[nt] = (f32x4){0.f, 0.f, 0.f, 0.f};

  for (int kc = 0; kc < 8; ++kc) {
#pragma unroll
    for (int nt = 0; nt < 8; ++nt) {
      bf16x8 bfr = *(const bf16x8*)(ab + (size_t)(nt * 16 + l15) * C +
                                    kc * 32 + quad * 8);
      acc[nt] = __builtin_amdgcn_mfma_f32_16x16x32_bf16(af[kc], bfr, acc[nt], 0, 0, 0);
    }
  }

#pragma unroll
  for (int nt = 0; nt < 8; ++nt) {
    const int pix = pix0 + nt * 16 + l15;
    const float gf = 1.f + gate[(b * 32 + (pix >> 5)) * 16 + ((pix & 31) >> 1)];
#pragma unroll
    for (int r = 0; r < 4; ++r) {
      const int o = o0 + 4 * quad + r;
      out[((size_t)b * C + o) * NPIX + pix] = acc[nt][r] * gf + bout[o];
    }
  }
}

// ---------------------------------------------------------------------------
extern "C" void kernel_launch(void* const* d_in, const int* in_sizes, int n_in,
                              void* d_out, int out_size, void* d_ws, size_t ws_size,
                              hipStream_t stream) {
  const float* x    = (const float*)d_in[0];
  const float* wqkv = (const float*)d_in[1];
  const float* wout = (const float*)d_in[2];
  const float* bout = (const float*)d_in[3];
  const float* wg1  = (const float*)d_in[4];
  const float* bg1  = (const float*)d_in[5];
  const float* wg2  = (const float*)d_in[6];
  const float* bg2  = (const float*)d_in[7];
  float* out = (float*)d_out;

  const size_t SZ = (size_t)B * HEADS * NPIX * D;   // 2,097,152
  u16* XT = (u16*)d_ws;
  u16* WQ = XT + SZ;
  u16* WO = WQ + (size_t)OC * C;
  u16* Q  = WO + (size_t)C * C;
  u16* Kq = Q + SZ;
  u16* VT = Kq + SZ;
  float* DIAG = (float*)(VT + SZ);
  float* COL  = DIAG + 256;
  float* GATE = COL + 2048;
  u16* AOT = XT;   // alias: XT dead after k_qkv_mfma

  hipLaunchKernelGGL(k_prep, dim3(768), dim3(256), 0, stream,
                     x, wqkv, wout, WQ, WO, XT);
  hipLaunchKernelGGL(k_qkv_mfma, dim3(12, 8, B), dim3(256), 0, stream,
                     XT, WQ, Q, Kq, VT);
  hipLaunchKernelGGL(k_red, dim3(72), dim3(256), 0, stream,
                     (const uint*)Q, (const uint*)Kq, VT, DIAG, COL);
  hipLaunchKernelGGL(k_attn, dim3(16, 64), dim3(256), 0, stream,
                     Q, Kq, VT, DIAG, COL, AOT);
  hipLaunchKernelGGL(k_gate, dim3(32, B), dim3(256), 0, stream,
                     x, wg1, bg1, wg2, bg2, GATE);
  hipLaunchKernelGGL(k_out_mfma, dim3(4, 8, B), dim3(256), 0, stream,
                     AOT, WO, bout, GATE, out);
}